// Round 3
// baseline (698.773 us; speedup 1.0000x reference)
//
#include <hip/hip_runtime.h>

typedef __attribute__((ext_vector_type(4))) float f32x4;
typedef __attribute__((ext_vector_type(8))) short short8;
typedef __attribute__((ext_vector_type(4))) unsigned short u16x4;
typedef __attribute__((ext_vector_type(8))) unsigned short u16x8;

#define AS1 __attribute__((address_space(1)))
#define AS3 __attribute__((address_space(3)))

__device__ __forceinline__ unsigned short f2bf(float f) {
  unsigned u = __float_as_uint(f);
  return (unsigned short)((u + 0x7FFFu + ((u >> 16) & 1u)) >> 16);
}
__device__ __forceinline__ unsigned short f2bf_fast(float f) {
  return (unsigned short)((__float_as_uint(f) + 0x8000u) >> 16);
}

// ---------- LayerNorm fp32 -> bf16 into zero-padded (B, 3+N+3, D) ----------
__global__ __launch_bounds__(256) void ln_kernel(
    const float* __restrict__ x, const float* __restrict__ lw,
    const float* __restrict__ lb, unsigned short* __restrict__ xpad) {
  __shared__ float red[8];
  int row = blockIdx.x;                  // 0..8191
  int b = row >> 12, n = row & 4095;
  const float* xr = x + (size_t)row * 1024;
  int c = threadIdx.x * 4;
  f32x4 v = *(const f32x4*)(xr + c);
  float s = v[0] + v[1] + v[2] + v[3];
  float sq = v[0]*v[0] + v[1]*v[1] + v[2]*v[2] + v[3]*v[3];
#pragma unroll
  for (int off = 32; off; off >>= 1) {
    s  += __shfl_xor(s, off, 64);
    sq += __shfl_xor(sq, off, 64);
  }
  int w = threadIdx.x >> 6;
  if ((threadIdx.x & 63) == 0) { red[w*2] = s; red[w*2+1] = sq; }
  __syncthreads();
  float S  = red[0]+red[2]+red[4]+red[6];
  float SQ = red[1]+red[3]+red[5]+red[7];
  float mean = S * (1.0f/1024.0f);
  float var  = SQ * (1.0f/1024.0f) - mean*mean;
  float rstd = rsqrtf(var + 1e-5f);
  f32x4 wv = *(const f32x4*)(lw + c);
  f32x4 bv = *(const f32x4*)(lb + c);
  u16x4 o;
#pragma unroll
  for (int r = 0; r < 4; ++r) o[r] = f2bf((v[r]-mean)*rstd*wv[r] + bv[r]);
  *(u16x4*)(xpad + (((size_t)(b*4102 + n + 3)) << 10) + c) = o;
}

// ---------- Repack W (O,I,K) fp32 -> Bt (O rows, kk=k*1024+i) bf16 via LDS ----------
__global__ __launch_bounds__(256) void repack_kernel(
    const float* __restrict__ Wk, const float* __restrict__ Wv,
    const float* __restrict__ Wq, unsigned short* __restrict__ Wt) {
  __shared__ unsigned short t[7168];
  const float* W = (blockIdx.y == 0) ? Wk : (blockIdx.y == 1) ? Wv : Wq;
  int o = blockIdx.x;
  const float* row = W + (size_t)o * 7168;
  unsigned short* orow = Wt + (size_t)blockIdx.y * 7168 * 1024 + (size_t)o * 7168;
#pragma unroll
  for (int p = 0; p < 7; ++p) {
    int idx = p*1024 + threadIdx.x*4;
    f32x4 v = *(const f32x4*)(row + idx);
#pragma unroll
    for (int e = 0; e < 4; ++e) {
      unsigned j = idx + e;
      unsigned i = (j * 149797u) >> 20;   // j/7
      unsigned k = j - i*7;
      t[k*1024 + i] = f2bf(v[e]);
    }
  }
  __syncthreads();
#pragma unroll
  for (int p = 0; p < 7; ++p) {
    int idx = p*1024 + threadIdx.x*4;
    *(u16x4*)(orow + idx) = *(const u16x4*)(t + idx);
  }
}

// ---------- All conv GEMMs, one launch. y<128: K/V interleaved (y&1). y>=128: Q. ----------
// Outputs in attention-fragment layouts:
//   Ksg[bh][kd2][n4096][32], Vsg[bh][nc128][d64][32], Qsg[bh][kd2][m1024][32], Qf row-major fp32.
__global__ __launch_bounds__(256) void conv_all(
    const unsigned short* __restrict__ Apad,
    const unsigned short* __restrict__ Wt,
    unsigned short* __restrict__ Ksg, unsigned short* __restrict__ Vsg,
    unsigned short* __restrict__ Qsg, float* __restrict__ Qf) {
  __shared__ unsigned short As[4096];
  __shared__ unsigned short Bs[4096];
  const int tid = threadIdx.x;
  const int w = tid >> 6, l = tid & 63;
  const int n0 = blockIdx.x << 7;
  const int y = blockIdx.y;
  const int mode = (y < 128) ? (y & 1) : 2;    // 0=K,1=V,2=Q
  const int r0 = (y < 128 ? (y >> 1) : (y - 128)) << 7;
  const unsigned short* Bt = Wt + (size_t)mode * 7168 * 1024;
  const int srow = l >> 2, schunk = l & 3;

  size_t abase[2], bbase[2];
#pragma unroll
  for (int p = 0; p < 2; ++p) {
    int r = r0 + ((p*4 + w) << 4) + srow;
    int bb, nn;
    if (mode == 2) { bb = r >> 10; nn = (r & 1023) << 2; }
    else           { bb = r >> 12; nn = r & 4095; }
    abase[p] = (((size_t)(bb*4102 + nn)) << 10) + schunk*8;
    int nc = n0 + ((p*4 + w) << 4) + srow;
    bbase[p] = (size_t)nc * 7168 + schunk*8;
  }

  f32x4 acc[4][4] = {};
  const int wm = (w >> 1) << 6, wn = (w & 1) << 6;
  const int quad = l >> 4, lc = l & 15;

  for (int k0 = 0; k0 < 7168; k0 += 32) {
    __syncthreads();
#pragma unroll
    for (int p = 0; p < 2; ++p) {
      __builtin_amdgcn_global_load_lds((const AS1 void*)(Apad + abase[p] + k0),
                                       (AS3 void*)(As + ((p*4 + w) << 9)), 16, 0, 0);
      __builtin_amdgcn_global_load_lds((const AS1 void*)(Bt + bbase[p] + k0),
                                       (AS3 void*)(Bs + ((p*4 + w) << 9)), 16, 0, 0);
    }
    __syncthreads();
    short8 af[4], bf[4];
#pragma unroll
    for (int i = 0; i < 4; ++i) {
      af[i] = *(const short8*)(As + (wm + (i<<4) + lc)*32 + (quad<<3));
      bf[i] = *(const short8*)(Bs + (wn + (i<<4) + lc)*32 + (quad<<3));
    }
#pragma unroll
    for (int i = 0; i < 4; ++i)
#pragma unroll
      for (int j = 0; j < 4; ++j)
        acc[i][j] = __builtin_amdgcn_mfma_f32_16x16x32_bf16(af[i], bf[j], acc[i][j], 0, 0, 0);
  }

  if (mode == 0) {         // K -> Ksg[bh][d>>5][n][d&31]
#pragma unroll
    for (int i = 0; i < 4; ++i) {
      int rg = r0 + wm + (i<<4) + quad*4;
      int b = rg >> 12, nb = rg & 4095;
#pragma unroll
      for (int j = 0; j < 4; ++j) {
        int cg = n0 + wn + (j<<4) + lc;
        int h = cg >> 6, kd = (cg >> 5) & 1, d32 = cg & 31;
        size_t base = ((size_t)((b*16 + h)*2 + kd) * 4096 + nb) * 32 + d32;
#pragma unroll
        for (int rr = 0; rr < 4; ++rr)
          Ksg[base + (size_t)rr*32] = f2bf(acc[i][j][rr]);
      }
    }
  } else if (mode == 1) {  // V -> Vsg[bh][n>>5][d][n&31]
#pragma unroll
    for (int i = 0; i < 4; ++i) {
      int rg = r0 + wm + (i<<4) + quad*4;
      int b = rg >> 12, nb = rg & 4095;
      int nc = nb >> 5, nl = nb & 31;
#pragma unroll
      for (int j = 0; j < 4; ++j) {
        int cg = n0 + wn + (j<<4) + lc;
        int h = cg >> 6, d = cg & 63;
        u16x4 pv;
#pragma unroll
        for (int rr = 0; rr < 4; ++rr) pv[rr] = f2bf(acc[i][j][rr]);
        *(u16x4*)(Vsg + (((size_t)((b*16 + h)*128 + nc) * 64 + d) * 32 + nl)) = pv;
      }
    }
  } else {                 // Q -> Qsg[bh][d>>5][m][d&31] + Qf row-major fp32
#pragma unroll
    for (int i = 0; i < 4; ++i) {
      int rg = r0 + wm + (i<<4) + quad*4;
      int b = rg >> 10, mb = rg & 1023;
#pragma unroll
      for (int j = 0; j < 4; ++j) {
        int cg = n0 + wn + (j<<4) + lc;
        int h = cg >> 6, kd = (cg >> 5) & 1, d32 = cg & 31;
        size_t base = ((size_t)((b*16 + h)*2 + kd) * 1024 + mb) * 32 + d32;
#pragma unroll
        for (int rr = 0; rr < 4; ++rr) {
          float vv = acc[i][j][rr];
          Qsg[base + (size_t)rr*32] = f2bf(vv);
          Qf[((size_t)(rg + rr) << 10) + cg] = vv;
        }
      }
    }
  }
}

// ---------- Flash attention: 64 queries/block, N-tile=128, async fragment staging ----------
__global__ __launch_bounds__(256) void attn_kernel(
    const unsigned short* __restrict__ Ksg, const unsigned short* __restrict__ Vsg,
    const unsigned short* __restrict__ Qsg, const float* __restrict__ Qf,
    float* __restrict__ out) {
  __shared__ unsigned short Ks[8192];   // [kd2][n128][32]
  __shared__ unsigned short Vs[8192];   // [kn4][d64][32]
  __shared__ unsigned short Qs[4096];   // [kd2][m64][32]
  __shared__ unsigned short Ps[8704];   // per-wave 16m x 136 (128n + pad8)
  const int tid = threadIdx.x, w = tid >> 6, l = tid & 63;
  // XCD swizzle: bh = (g&7) + 8*((g>>3)&3) -> each XCD serves 4 heads (4MB K+V = one L2)
  const int g = blockIdx.x;
  const int bh = (g & 7) + ((( g >> 3) & 3) << 3);
  const int qt = g >> 5;
  const int b = bh >> 4, h = bh & 15;
  const int m0 = qt << 6;
  const int quad = l >> 4, lc = l & 15;
  const float C = 0.18033688011112042f;  // log2(e)/8

  const unsigned short* KgT = Ksg + ((size_t)bh << 18);
  const unsigned short* VgT = Vsg + ((size_t)bh << 18);
  const unsigned short* QgT = Qsg + ((size_t)bh << 16);

  // stage Q (8 KB): 8 wave-copies of 1 KB, 2 per wave
#pragma unroll
  for (int p = 0; p < 2; ++p) {
    int t = w*2 + p;
    int kd = t >> 2, ml = (t & 3) << 4;
    __builtin_amdgcn_global_load_lds(
        (const AS1 void*)(QgT + ((size_t)((kd << 10) + m0 + ml) << 5) + l*8),
        (AS3 void*)(Qs + (t << 9)), 16, 0, 0);
  }

  float l_run = 0.f;
  f32x4 oacc[4] = {};
  unsigned short* Pw = Ps + w*2176;

  for (int it = 0; it < 32; ++it) {
    int n0 = it << 7;
    __syncthreads();
#pragma unroll
    for (int p = 0; p < 4; ++p) {
      int t = (w << 2) + p;
      __builtin_amdgcn_global_load_lds(
          (const AS1 void*)(KgT + ((size_t)(((t >> 3) << 12) + n0 + ((t & 7) << 4)) << 5) + l*8),
          (AS3 void*)(Ks + (t << 9)), 16, 0, 0);
      __builtin_amdgcn_global_load_lds(
          (const AS1 void*)(VgT + ((size_t)((((n0 >> 5) + (t >> 2)) << 6) + ((t & 3) << 4)) << 5) + l*8),
          (AS3 void*)(Vs + (t << 9)), 16, 0, 0);
    }
    __syncthreads();

    short8 ak[8][2];
#pragma unroll
    for (int k = 0; k < 2; ++k)
#pragma unroll
      for (int ni = 0; ni < 8; ++ni)
        ak[ni][k] = *(const short8*)(Ks + (k << 12) + ((ni<<4) + lc)*32 + (quad<<3));

    f32x4 sv[8] = {};
#pragma unroll
    for (int k = 0; k < 2; ++k) {
      short8 bq = *(const short8*)(Qs + (k << 11) + ((w<<4) + lc)*32 + (quad<<3));
#pragma unroll
      for (int ni = 0; ni < 8; ++ni)
        sv[ni] = __builtin_amdgcn_mfma_f32_16x16x32_bf16(ak[ni][k], bq, sv[ni], 0, 0, 0);
    }

    float su = 0.f;
#pragma unroll
    for (int ni = 0; ni < 8; ++ni) {
      u16x4 pv;
#pragma unroll
      for (int rr = 0; rr < 4; ++rr) {
        float pp = __builtin_amdgcn_exp2f(sv[ni][rr] * C);
        su += pp;
        pv[rr] = f2bf_fast(pp);
      }
      *(u16x4*)(Pw + lc*136 + (ni<<4) + (quad<<2)) = pv;
    }
    su += __shfl_xor(su, 16, 64);
    su += __shfl_xor(su, 32, 64);
    l_run += su;

    // Ps is per-wave: compiler lgkmcnt orders write->read, no barrier needed
#pragma unroll
    for (int kn = 0; kn < 4; ++kn) {
      short8 bp = *(const short8*)(Pw + lc*136 + (kn<<5) + (quad<<3));
#pragma unroll
      for (int dt = 0; dt < 4; ++dt) {
        short8 av = *(const short8*)(Vs + (kn << 11) + ((dt<<4) + lc)*32 + (quad<<3));
        oacc[dt] = __builtin_amdgcn_mfma_f32_16x16x32_bf16(av, bp, oacc[dt], 0, 0, 0);
      }
    }
  }

  float invl = 1.0f / l_run;
  int m = m0 + (w<<4) + lc;
#pragma unroll
  for (int dt = 0; dt < 4; ++dt) {
    int d = (dt<<4) + (quad<<2);
    size_t off = (((size_t)(b << 10) + m) << 10) + (h << 6) + d;
    f32x4 qv = *(const f32x4*)(Qf + off);
    f32x4 ov;
#pragma unroll
    for (int rr = 0; rr < 4; ++rr) ov[rr] = oacc[dt][rr]*invl + qv[rr];
    *(f32x4*)(out + off) = ov;
  }
}

extern "C" void kernel_launch(void* const* d_in, const int* in_sizes, int n_in,
                              void* d_out, int out_size, void* d_ws, size_t ws_size,
                              hipStream_t stream) {
  const float* x  = (const float*)d_in[0];
  const float* lw = (const float*)d_in[1];
  const float* lb = (const float*)d_in[2];
  const float* Wk = (const float*)d_in[3];
  const float* Wv = (const float*)d_in[4];
  const float* Wq = (const float*)d_in[5];
  float* out = (float*)d_out;

  char* ws = (char*)d_ws;
  size_t off = 0;
  unsigned short* xpad = (unsigned short*)(ws + off); off += (size_t)2*4102*1024*2;
  unsigned short* Wt   = (unsigned short*)(ws + off); off += (size_t)3*7168*1024*2;
  unsigned short* Ksg  = (unsigned short*)(ws + off); off += (size_t)32*2*4096*32*2;
  unsigned short* Vsg  = (unsigned short*)(ws + off); off += (size_t)32*128*64*32*2;
  unsigned short* Qsg  = (unsigned short*)(ws + off); off += (size_t)32*2*1024*32*2;
  float*          Qf   = (float*)(ws + off);          off += (size_t)2048*1024*4;

  // zero only the 3-row pads (front/back per batch)
  for (int b = 0; b < 2; ++b) {
    hipMemsetAsync(xpad + (size_t)b*4102*1024, 0, 3*1024*2, stream);
    hipMemsetAsync(xpad + ((size_t)b*4102 + 4099)*1024, 0, 3*1024*2, stream);
  }
  ln_kernel<<<dim3(8192), dim3(256), 0, stream>>>(x, lw, lb, xpad);
  repack_kernel<<<dim3(1024, 3), dim3(256), 0, stream>>>(Wk, Wv, Wq, Wt);
  conv_all<<<dim3(8, 144), dim3(256), 0, stream>>>(xpad, Wt, Ksg, Vsg, Qsg, Qf);
  attn_kernel<<<dim3(512), dim3(256), 0, stream>>>(Ksg, Vsg, Qsg, Qf, out);
}

// Round 4
// 692.452 us; speedup vs baseline: 1.0091x; 1.0091x over previous
//
#include <hip/hip_runtime.h>

typedef __attribute__((ext_vector_type(4))) float f32x4;
typedef __attribute__((ext_vector_type(16))) float f32x16;
typedef __attribute__((ext_vector_type(8))) short short8;
typedef __attribute__((ext_vector_type(4))) unsigned short u16x4;
typedef __attribute__((ext_vector_type(8))) unsigned short u16x8;

#define AS1 __attribute__((address_space(1)))
#define AS3 __attribute__((address_space(3)))

__device__ __forceinline__ unsigned short f2bf(float f) {
  unsigned u = __float_as_uint(f);
  return (unsigned short)((u + 0x7FFFu + ((u >> 16) & 1u)) >> 16);
}
__device__ __forceinline__ unsigned short f2bf_fast(float f) {
  return (unsigned short)((__float_as_uint(f) + 0x8000u) >> 16);
}

// ---------- LayerNorm fp32 -> bf16 into zero-padded (B, 3+N+3, D) ----------
__global__ __launch_bounds__(256) void ln_kernel(
    const float* __restrict__ x, const float* __restrict__ lw,
    const float* __restrict__ lb, unsigned short* __restrict__ xpad) {
  __shared__ float red[8];
  int row = blockIdx.x;                  // 0..8191
  int b = row >> 12, n = row & 4095;
  const float* xr = x + (size_t)row * 1024;
  int c = threadIdx.x * 4;
  f32x4 v = *(const f32x4*)(xr + c);
  float s = v[0] + v[1] + v[2] + v[3];
  float sq = v[0]*v[0] + v[1]*v[1] + v[2]*v[2] + v[3]*v[3];
#pragma unroll
  for (int off = 32; off; off >>= 1) {
    s  += __shfl_xor(s, off, 64);
    sq += __shfl_xor(sq, off, 64);
  }
  int w = threadIdx.x >> 6;
  if ((threadIdx.x & 63) == 0) { red[w*2] = s; red[w*2+1] = sq; }
  __syncthreads();
  float S  = red[0]+red[2]+red[4]+red[6];
  float SQ = red[1]+red[3]+red[5]+red[7];
  float mean = S * (1.0f/1024.0f);
  float var  = SQ * (1.0f/1024.0f) - mean*mean;
  float rstd = rsqrtf(var + 1e-5f);
  f32x4 wv = *(const f32x4*)(lw + c);
  f32x4 bv = *(const f32x4*)(lb + c);
  u16x4 o;
#pragma unroll
  for (int r = 0; r < 4; ++r) o[r] = f2bf((v[r]-mean)*rstd*wv[r] + bv[r]);
  *(u16x4*)(xpad + (((size_t)(b*4102 + n + 3)) << 10) + c) = o;
}

// ---------- Repack W (O,I,K) fp32 -> Bt rows (kk=k*1024+i) bf16 via LDS ----------
// y=0 -> WtKV row o (K); y=1 -> WtKV row 1024+o (V); y=2 -> WtQ row o.
__global__ __launch_bounds__(256) void repack_kernel(
    const float* __restrict__ Wk, const float* __restrict__ Wv,
    const float* __restrict__ Wq, unsigned short* __restrict__ WtKV,
    unsigned short* __restrict__ WtQ) {
  __shared__ unsigned short t[7168];
  const float* W = (blockIdx.y == 0) ? Wk : (blockIdx.y == 1) ? Wv : Wq;
  int o = blockIdx.x;
  const float* row = W + (size_t)o * 7168;
  unsigned short* orow =
      (blockIdx.y == 2) ? (WtQ + (size_t)o * 7168)
                        : (WtKV + ((size_t)o + (blockIdx.y == 1 ? 1024 : 0)) * 7168);
#pragma unroll
  for (int p = 0; p < 7; ++p) {
    int idx = p*1024 + threadIdx.x*4;
    f32x4 v = *(const f32x4*)(row + idx);
#pragma unroll
    for (int e = 0; e < 4; ++e) {
      unsigned j = idx + e;
      unsigned i = (j * 149797u) >> 20;   // j/7
      unsigned k = j - i*7;
      t[k*1024 + i] = f2bf(v[e]);
    }
  }
  __syncthreads();
#pragma unroll
  for (int p = 0; p < 7; ++p) {
    int idx = p*1024 + threadIdx.x*4;
    *(u16x4*)(orow + idx) = *(const u16x4*)(t + idx);
  }
}

// ---------- K+V combined GEMM: C(8192 x 2048) = A(im2col) x [Wk;Wv]^T, 32x32x16 MFMA ----------
// 1024 blocks; xcol swizzled so each XCD owns 2 column panels (L2-resident B slab).
// Epilogue (block-uniform): xcol<8 -> Ksg[bh][kd2][n4096][32]; else Vsg[bh][nc128][d64][32].
__global__ __launch_bounds__(256, 4) void conv_kv(
    const unsigned short* __restrict__ Apad,
    const unsigned short* __restrict__ WtKV,
    unsigned short* __restrict__ Ksg, unsigned short* __restrict__ Vsg) {
  __shared__ unsigned short As[4096];
  __shared__ unsigned short Bs[4096];
  const int g = blockIdx.x;
  const int xcol = ((g & 7) << 1) | ((g >> 3) & 1);
  const int yr = g >> 4;
  const int n0 = xcol << 7;
  const int r0 = yr << 7;
  const int tid = threadIdx.x;
  const int w = tid >> 6, l = tid & 63;
  const int srow = l >> 2, schunk = l & 3;

  size_t abase[2], bbase[2];
#pragma unroll
  for (int p = 0; p < 2; ++p) {
    int r = r0 + ((p*4 + w) << 4) + srow;
    int bb = r >> 12, nn = r & 4095;
    abase[p] = (((size_t)(bb*4102 + nn)) << 10) + schunk*8;
    int nc = n0 + ((p*4 + w) << 4) + srow;
    bbase[p] = (size_t)nc * 7168 + schunk*8;
  }

  f32x16 acc[2][2] = {};
  const int wm = (w >> 1) << 6, wn = (w & 1) << 6;   // wave quadrant (64x64)
  const int l31 = l & 31, lh = l >> 5;

  for (int k0 = 0; k0 < 7168; k0 += 32) {
    __syncthreads();
#pragma unroll
    for (int p = 0; p < 2; ++p) {
      __builtin_amdgcn_global_load_lds((const AS1 void*)(Apad + abase[p] + k0),
                                       (AS3 void*)(As + ((p*4 + w) << 9)), 16, 0, 0);
      __builtin_amdgcn_global_load_lds((const AS1 void*)(WtKV + bbase[p] + k0),
                                       (AS3 void*)(Bs + ((p*4 + w) << 9)), 16, 0, 0);
    }
    __syncthreads();
    short8 af[2][2], bf[2][2];   // [tile][k-half]
#pragma unroll
    for (int i = 0; i < 2; ++i)
#pragma unroll
      for (int s = 0; s < 2; ++s) {
        af[i][s] = *(const short8*)(As + (wm + (i<<5) + l31)*32 + (s<<4) + (lh<<3));
        bf[i][s] = *(const short8*)(Bs + (wn + (i<<5) + l31)*32 + (s<<4) + (lh<<3));
      }
#pragma unroll
    for (int s = 0; s < 2; ++s)
#pragma unroll
      for (int i = 0; i < 2; ++i)
#pragma unroll
        for (int j = 0; j < 2; ++j)
          acc[i][j] = __builtin_amdgcn_mfma_f32_32x32x16_bf16(af[i][s], bf[j][s], acc[i][j], 0, 0, 0);
  }

  // C/D mapping (32x32): col = l&31, row = (r&3) + 8*(r>>2) + 4*(l>>5)
  if (xcol < 8) {   // K output
#pragma unroll
    for (int i = 0; i < 2; ++i) {
      int rgb = r0 + wm + (i<<5);            // multiple of 32
      int b = rgb >> 12, nbase = rgb & 4095;
#pragma unroll
      for (int j = 0; j < 2; ++j) {
        int cg = n0 + wn + (j<<5) + l31;     // 0..1023
        int h = cg >> 6, kd = (cg >> 5) & 1;
        size_t base = ((size_t)(((b*16 + h)*2 + kd)) << 12) * 32 + (size_t)(cg & 31);
#pragma unroll
        for (int r = 0; r < 16; ++r) {
          int nb = nbase + (r & 3) + ((r >> 2) << 3) + (lh << 2);
          Ksg[base + ((size_t)nb << 5)] = f2bf(acc[i][j][r]);
        }
      }
    }
  } else {          // V output
#pragma unroll
    for (int i = 0; i < 2; ++i) {
      int rgb = r0 + wm + (i<<5);
      int b = rgb >> 12, nbase = rgb & 4095;
      int nc = nbase >> 5;
#pragma unroll
      for (int j = 0; j < 2; ++j) {
        int c = n0 + wn + (j<<5) + l31 - 1024;   // 0..1023
        int h = c >> 6, d = c & 63;
        size_t rowbase = ((size_t)((b*16 + h)*128 + nc) * 64 + d) << 5;
#pragma unroll
        for (int g2 = 0; g2 < 4; ++g2) {
          u16x4 pv;
#pragma unroll
          for (int e = 0; e < 4; ++e) pv[e] = f2bf(acc[i][j][g2*4 + e]);
          *(u16x4*)(Vsg + rowbase + (g2 << 3) + (lh << 2)) = pv;
        }
      }
    }
  }
}

// ---------- Q conv GEMM (strided rows), 16x16x32, fragment-layout + fp32 outputs ----------
__global__ __launch_bounds__(256) void conv_q(
    const unsigned short* __restrict__ Apad,
    const unsigned short* __restrict__ WtQ,
    unsigned short* __restrict__ Qsg, float* __restrict__ Qf) {
  __shared__ unsigned short As[4096];
  __shared__ unsigned short Bs[4096];
  const int tid = threadIdx.x;
  const int w = tid >> 6, l = tid & 63;
  const int n0 = blockIdx.x << 7;
  const int r0 = blockIdx.y << 7;
  const int srow = l >> 2, schunk = l & 3;

  size_t abase[2], bbase[2];
#pragma unroll
  for (int p = 0; p < 2; ++p) {
    int r = r0 + ((p*4 + w) << 4) + srow;
    int bb = r >> 10, nn = (r & 1023) << 2;
    abase[p] = (((size_t)(bb*4102 + nn)) << 10) + schunk*8;
    int nc = n0 + ((p*4 + w) << 4) + srow;
    bbase[p] = (size_t)nc * 7168 + schunk*8;
  }

  f32x4 acc[4][4] = {};
  const int wm = (w >> 1) << 6, wn = (w & 1) << 6;
  const int quad = l >> 4, lc = l & 15;

  for (int k0 = 0; k0 < 7168; k0 += 32) {
    __syncthreads();
#pragma unroll
    for (int p = 0; p < 2; ++p) {
      __builtin_amdgcn_global_load_lds((const AS1 void*)(Apad + abase[p] + k0),
                                       (AS3 void*)(As + ((p*4 + w) << 9)), 16, 0, 0);
      __builtin_amdgcn_global_load_lds((const AS1 void*)(WtQ + bbase[p] + k0),
                                       (AS3 void*)(Bs + ((p*4 + w) << 9)), 16, 0, 0);
    }
    __syncthreads();
    short8 af[4], bf[4];
#pragma unroll
    for (int i = 0; i < 4; ++i) {
      af[i] = *(const short8*)(As + (wm + (i<<4) + lc)*32 + (quad<<3));
      bf[i] = *(const short8*)(Bs + (wn + (i<<4) + lc)*32 + (quad<<3));
    }
#pragma unroll
    for (int i = 0; i < 4; ++i)
#pragma unroll
      for (int j = 0; j < 4; ++j)
        acc[i][j] = __builtin_amdgcn_mfma_f32_16x16x32_bf16(af[i], bf[j], acc[i][j], 0, 0, 0);
  }

#pragma unroll
  for (int i = 0; i < 4; ++i) {
    int rg = r0 + wm + (i<<4) + quad*4;
    int b = rg >> 10, mb = rg & 1023;
#pragma unroll
    for (int j = 0; j < 4; ++j) {
      int cg = n0 + wn + (j<<4) + lc;
      int h = cg >> 6, kd = (cg >> 5) & 1, d32 = cg & 31;
      size_t base = ((size_t)((b*16 + h)*2 + kd) * 1024 + mb) * 32 + d32;
#pragma unroll
      for (int rr = 0; rr < 4; ++rr) {
        float vv = acc[i][j][rr];
        Qsg[base + (size_t)rr*32] = f2bf(vv);
        Qf[((size_t)(rg + rr) << 10) + cg] = vv;
      }
    }
  }
}

// ---------- Flash attention: 64 queries/block, N-tile=128, async fragment staging ----------
__global__ __launch_bounds__(256) void attn_kernel(
    const unsigned short* __restrict__ Ksg, const unsigned short* __restrict__ Vsg,
    const unsigned short* __restrict__ Qsg, const float* __restrict__ Qf,
    float* __restrict__ out) {
  __shared__ unsigned short Ks[8192];   // [kd2][n128][32]
  __shared__ unsigned short Vs[8192];   // [kn4][d64][32]
  __shared__ unsigned short Qs[4096];   // [kd2][m64][32]
  __shared__ unsigned short Ps[8704];   // per-wave 16m x 136 (128n + pad8)
  const int tid = threadIdx.x, w = tid >> 6, l = tid & 63;
  const int g = blockIdx.x;
  const int bh = (g & 7) + ((( g >> 3) & 3) << 3);
  const int qt = g >> 5;
  const int b = bh >> 4, h = bh & 15;
  const int m0 = qt << 6;
  const int quad = l >> 4, lc = l & 15;
  const float C = 0.18033688011112042f;  // log2(e)/8

  const unsigned short* KgT = Ksg + ((size_t)bh << 18);
  const unsigned short* VgT = Vsg + ((size_t)bh << 18);
  const unsigned short* QgT = Qsg + ((size_t)bh << 16);

#pragma unroll
  for (int p = 0; p < 2; ++p) {
    int t = w*2 + p;
    int kd = t >> 2, ml = (t & 3) << 4;
    __builtin_amdgcn_global_load_lds(
        (const AS1 void*)(QgT + ((size_t)((kd << 10) + m0 + ml) << 5) + l*8),
        (AS3 void*)(Qs + (t << 9)), 16, 0, 0);
  }

  float l_run = 0.f;
  f32x4 oacc[4] = {};
  unsigned short* Pw = Ps + w*2176;

  for (int it = 0; it < 32; ++it) {
    int n0 = it << 7;
    __syncthreads();
#pragma unroll
    for (int p = 0; p < 4; ++p) {
      int t = (w << 2) + p;
      __builtin_amdgcn_global_load_lds(
          (const AS1 void*)(KgT + ((size_t)(((t >> 3) << 12) + n0 + ((t & 7) << 4)) << 5) + l*8),
          (AS3 void*)(Ks + (t << 9)), 16, 0, 0);
      __builtin_amdgcn_global_load_lds(
          (const AS1 void*)(VgT + ((size_t)((((n0 >> 5) + (t >> 2)) << 6) + ((t & 3) << 4)) << 5) + l*8),
          (AS3 void*)(Vs + (t << 9)), 16, 0, 0);
    }
    __syncthreads();

    short8 ak[8][2];
#pragma unroll
    for (int k = 0; k < 2; ++k)
#pragma unroll
      for (int ni = 0; ni < 8; ++ni)
        ak[ni][k] = *(const short8*)(Ks + (k << 12) + ((ni<<4) + lc)*32 + (quad<<3));

    f32x4 sv[8] = {};
#pragma unroll
    for (int k = 0; k < 2; ++k) {
      short8 bq = *(const short8*)(Qs + (k << 11) + ((w<<4) + lc)*32 + (quad<<3));
#pragma unroll
      for (int ni = 0; ni < 8; ++ni)
        sv[ni] = __builtin_amdgcn_mfma_f32_16x16x32_bf16(ak[ni][k], bq, sv[ni], 0, 0, 0);
    }

    float su = 0.f;
#pragma unroll
    for (int ni = 0; ni < 8; ++ni) {
      u16x4 pv;
#pragma unroll
      for (int rr = 0; rr < 4; ++rr) {
        float pp = __builtin_amdgcn_exp2f(sv[ni][rr] * C);
        su += pp;
        pv[rr] = f2bf_fast(pp);
      }
      *(u16x4*)(Pw + lc*136 + (ni<<4) + (quad<<2)) = pv;
    }
    su += __shfl_xor(su, 16, 64);
    su += __shfl_xor(su, 32, 64);
    l_run += su;

#pragma unroll
    for (int kn = 0; kn < 4; ++kn) {
      short8 bp = *(const short8*)(Pw + lc*136 + (kn<<5) + (quad<<3));
#pragma unroll
      for (int dt = 0; dt < 4; ++dt) {
        short8 av = *(const short8*)(Vs + (kn << 11) + ((dt<<4) + lc)*32 + (quad<<3));
        oacc[dt] = __builtin_amdgcn_mfma_f32_16x16x32_bf16(av, bp, oacc[dt], 0, 0, 0);
      }
    }
  }

  float invl = 1.0f / l_run;
  int m = m0 + (w<<4) + lc;
#pragma unroll
  for (int dt = 0; dt < 4; ++dt) {
    int d = (dt<<4) + (quad<<2);
    size_t off = (((size_t)(b << 10) + m) << 10) + (h << 6) + d;
    f32x4 qv = *(const f32x4*)(Qf + off);
    f32x4 ov;
#pragma unroll
    for (int rr = 0; rr < 4; ++rr) ov[rr] = oacc[dt][rr]*invl + qv[rr];
    *(f32x4*)(out + off) = ov;
  }
}

extern "C" void kernel_launch(void* const* d_in, const int* in_sizes, int n_in,
                              void* d_out, int out_size, void* d_ws, size_t ws_size,
                              hipStream_t stream) {
  const float* x  = (const float*)d_in[0];
  const float* lw = (const float*)d_in[1];
  const float* lb = (const float*)d_in[2];
  const float* Wk = (const float*)d_in[3];
  const float* Wv = (const float*)d_in[4];
  const float* Wq = (const float*)d_in[5];
  float* out = (float*)d_out;

  char* ws = (char*)d_ws;
  size_t off = 0;
  unsigned short* xpad = (unsigned short*)(ws + off); off += (size_t)2*4102*1024*2;
  unsigned short* WtKV = (unsigned short*)(ws + off); off += (size_t)2048*7168*2;
  unsigned short* WtQ  = (unsigned short*)(ws + off); off += (size_t)1024*7168*2;
  unsigned short* Ksg  = (unsigned short*)(ws + off); off += (size_t)32*2*4096*32*2;
  unsigned short* Vsg  = (unsigned short*)(ws + off); off += (size_t)32*128*64*32*2;
  unsigned short* Qsg  = (unsigned short*)(ws + off); off += (size_t)32*2*1024*32*2;
  float*          Qf   = (float*)(ws + off);          off += (size_t)2048*1024*4;

  for (int b = 0; b < 2; ++b) {
    hipMemsetAsync(xpad + (size_t)b*4102*1024, 0, 3*1024*2, stream);
    hipMemsetAsync(xpad + ((size_t)b*4102 + 4099)*1024, 0, 3*1024*2, stream);
  }
  ln_kernel<<<dim3(8192), dim3(256), 0, stream>>>(x, lw, lb, xpad);
  repack_kernel<<<dim3(1024, 3), dim3(256), 0, stream>>>(Wk, Wv, Wq, WtKV, WtQ);
  conv_kv<<<dim3(1024), dim3(256), 0, stream>>>(xpad, WtKV, Ksg, Vsg);
  conv_q<<<dim3(8, 16), dim3(256), 0, stream>>>(xpad, WtQ, Qsg, Qf);
  attn_kernel<<<dim3(512), dim3(256), 0, stream>>>(Ksg, Vsg, Qsg, Qf, out);
}

// Round 5
// 674.857 us; speedup vs baseline: 1.0354x; 1.0261x over previous
//
#include <hip/hip_runtime.h>

typedef __attribute__((ext_vector_type(4))) float f32x4;
typedef __attribute__((ext_vector_type(16))) float f32x16;
typedef __attribute__((ext_vector_type(8))) short short8;
typedef __attribute__((ext_vector_type(4))) unsigned short u16x4;
typedef __attribute__((ext_vector_type(8))) unsigned short u16x8;

#define AS1 __attribute__((address_space(1)))
#define AS3 __attribute__((address_space(3)))

__device__ __forceinline__ unsigned short f2bf(float f) {
  unsigned u = __float_as_uint(f);
  return (unsigned short)((u + 0x7FFFu + ((u >> 16) & 1u)) >> 16);
}
__device__ __forceinline__ unsigned short f2bf_fast(float f) {
  return (unsigned short)((__float_as_uint(f) + 0x8000u) >> 16);
}

// ---------- LayerNorm fp32 -> bf16 into zero-padded (B, 3+N+3, D) ----------
__global__ __launch_bounds__(256) void ln_kernel(
    const float* __restrict__ x, const float* __restrict__ lw,
    const float* __restrict__ lb, unsigned short* __restrict__ xpad) {
  __shared__ float red[8];
  int row = blockIdx.x;                  // 0..8191
  int b = row >> 12, n = row & 4095;
  const float* xr = x + (size_t)row * 1024;
  int c = threadIdx.x * 4;
  f32x4 v = *(const f32x4*)(xr + c);
  float s = v[0] + v[1] + v[2] + v[3];
  float sq = v[0]*v[0] + v[1]*v[1] + v[2]*v[2] + v[3]*v[3];
#pragma unroll
  for (int off = 32; off; off >>= 1) {
    s  += __shfl_xor(s, off, 64);
    sq += __shfl_xor(sq, off, 64);
  }
  int w = threadIdx.x >> 6;
  if ((threadIdx.x & 63) == 0) { red[w*2] = s; red[w*2+1] = sq; }
  __syncthreads();
  float S  = red[0]+red[2]+red[4]+red[6];
  float SQ = red[1]+red[3]+red[5]+red[7];
  float mean = S * (1.0f/1024.0f);
  float var  = SQ * (1.0f/1024.0f) - mean*mean;
  float rstd = rsqrtf(var + 1e-5f);
  f32x4 wv = *(const f32x4*)(lw + c);
  f32x4 bv = *(const f32x4*)(lb + c);
  u16x4 o;
#pragma unroll
  for (int r = 0; r < 4; ++r) o[r] = f2bf((v[r]-mean)*rstd*wv[r] + bv[r]);
  *(u16x4*)(xpad + (((size_t)(b*4102 + n + 3)) << 10) + c) = o;
}

// ---------- Repack W (O,I,K) fp32 -> Bt rows (kk=k*1024+i) bf16 via LDS ----------
__global__ __launch_bounds__(256) void repack_kernel(
    const float* __restrict__ Wk, const float* __restrict__ Wv,
    const float* __restrict__ Wq, unsigned short* __restrict__ WtKV,
    unsigned short* __restrict__ WtQ) {
  __shared__ unsigned short t[7168];
  const float* W = (blockIdx.y == 0) ? Wk : (blockIdx.y == 1) ? Wv : Wq;
  int o = blockIdx.x;
  const float* row = W + (size_t)o * 7168;
  unsigned short* orow =
      (blockIdx.y == 2) ? (WtQ + (size_t)o * 7168)
                        : (WtKV + ((size_t)o + (blockIdx.y == 1 ? 1024 : 0)) * 7168);
#pragma unroll
  for (int p = 0; p < 7; ++p) {
    int idx = p*1024 + threadIdx.x*4;
    f32x4 v = *(const f32x4*)(row + idx);
#pragma unroll
    for (int e = 0; e < 4; ++e) {
      unsigned j = idx + e;
      unsigned i = (j * 149797u) >> 20;   // j/7
      unsigned k = j - i*7;
      t[k*1024 + i] = f2bf(v[e]);
    }
  }
  __syncthreads();
#pragma unroll
  for (int p = 0; p < 7; ++p) {
    int idx = p*1024 + threadIdx.x*4;
    *(u16x4*)(orow + idx) = *(const u16x4*)(t + idx);
  }
}

// ---------- K+V combined GEMM, 32x32x16 MFMA, XOR-swizzled LDS chunks ----------
// Storage rule: chunk c (16B) of LDS row r lives at physical chunk c^(r&3).
__global__ __launch_bounds__(256, 4) void conv_kv(
    const unsigned short* __restrict__ Apad,
    const unsigned short* __restrict__ WtKV,
    unsigned short* __restrict__ Ksg, unsigned short* __restrict__ Vsg) {
  __shared__ unsigned short As[4096];
  __shared__ unsigned short Bs[4096];
  const int g = blockIdx.x;
  const int xcol = ((g & 7) << 1) | ((g >> 3) & 1);
  const int yr = g >> 4;
  const int n0 = xcol << 7;
  const int r0 = yr << 7;
  const int tid = threadIdx.x;
  const int w = tid >> 6, l = tid & 63;
  const int srow = l >> 2;
  const int schunk = (l ^ (l >> 2)) & 3;   // fetch swizzled source chunk

  size_t abase[2], bbase[2];
#pragma unroll
  for (int p = 0; p < 2; ++p) {
    int r = r0 + ((p*4 + w) << 4) + srow;
    int bb = r >> 12, nn = r & 4095;
    abase[p] = (((size_t)(bb*4102 + nn)) << 10) + schunk*8;
    int nc = n0 + ((p*4 + w) << 4) + srow;
    bbase[p] = (size_t)nc * 7168 + schunk*8;
  }

  f32x16 acc[2][2] = {};
  const int wm = (w >> 1) << 6, wn = (w & 1) << 6;   // wave quadrant (64x64)
  const int l31 = l & 31, lh = l >> 5, l3 = l & 3;

  for (int k0 = 0; k0 < 7168; k0 += 32) {
    __syncthreads();
#pragma unroll
    for (int p = 0; p < 2; ++p) {
      __builtin_amdgcn_global_load_lds((const AS1 void*)(Apad + abase[p] + k0),
                                       (AS3 void*)(As + ((p*4 + w) << 9)), 16, 0, 0);
      __builtin_amdgcn_global_load_lds((const AS1 void*)(WtKV + bbase[p] + k0),
                                       (AS3 void*)(Bs + ((p*4 + w) << 9)), 16, 0, 0);
    }
    __syncthreads();
    short8 af[2][2], bf[2][2];   // [tile][k-half]
#pragma unroll
    for (int i = 0; i < 2; ++i)
#pragma unroll
      for (int s = 0; s < 2; ++s) {
        int ch = (((s << 1) | lh) ^ l3) << 3;
        af[i][s] = *(const short8*)(As + (wm + (i<<5) + l31)*32 + ch);
        bf[i][s] = *(const short8*)(Bs + (wn + (i<<5) + l31)*32 + ch);
      }
#pragma unroll
    for (int s = 0; s < 2; ++s)
#pragma unroll
      for (int i = 0; i < 2; ++i)
#pragma unroll
        for (int j = 0; j < 2; ++j)
          acc[i][j] = __builtin_amdgcn_mfma_f32_32x32x16_bf16(af[i][s], bf[j][s], acc[i][j], 0, 0, 0);
  }

  // C/D mapping (32x32): col = l&31, row = (r&3) + 8*(r>>2) + 4*(l>>5)
  if (xcol < 8) {   // K output -> Ksg[bh][kd2][n4096][32]
#pragma unroll
    for (int i = 0; i < 2; ++i) {
      int rgb = r0 + wm + (i<<5);
      int b = rgb >> 12, nbase = rgb & 4095;
#pragma unroll
      for (int j = 0; j < 2; ++j) {
        int cg = n0 + wn + (j<<5) + l31;
        int h = cg >> 6, kd = (cg >> 5) & 1;
        size_t base = ((size_t)(((b*16 + h)*2 + kd)) << 12) * 32 + (size_t)(cg & 31);
#pragma unroll
        for (int r = 0; r < 16; ++r) {
          int nb = nbase + (r & 3) + ((r >> 2) << 3) + (lh << 2);
          Ksg[base + ((size_t)nb << 5)] = f2bf(acc[i][j][r]);
        }
      }
    }
  } else {          // V output -> Vsg[bh][n>>5][d][n&31]
#pragma unroll
    for (int i = 0; i < 2; ++i) {
      int rgb = r0 + wm + (i<<5);
      int b = rgb >> 12, nbase = rgb & 4095;
      int nc = nbase >> 5;
#pragma unroll
      for (int j = 0; j < 2; ++j) {
        int c = n0 + wn + (j<<5) + l31 - 1024;
        int h = c >> 6, d = c & 63;
        size_t rowbase = ((size_t)((b*16 + h)*128 + nc) * 64 + d) << 5;
#pragma unroll
        for (int g2 = 0; g2 < 4; ++g2) {
          u16x4 pv;
#pragma unroll
          for (int e = 0; e < 4; ++e) pv[e] = f2bf(acc[i][j][g2*4 + e]);
          *(u16x4*)(Vsg + rowbase + (g2 << 3) + (lh << 2)) = pv;
        }
      }
    }
  }
}

// ---------- Q conv GEMM (strided rows), 16x16x32, swizzled LDS ----------
__global__ __launch_bounds__(256) void conv_q(
    const unsigned short* __restrict__ Apad,
    const unsigned short* __restrict__ WtQ,
    unsigned short* __restrict__ Qsg, float* __restrict__ Qf) {
  __shared__ unsigned short As[4096];
  __shared__ unsigned short Bs[4096];
  const int tid = threadIdx.x;
  const int w = tid >> 6, l = tid & 63;
  const int n0 = blockIdx.x << 7;
  const int r0 = blockIdx.y << 7;
  const int srow = l >> 2;
  const int schunk = (l ^ (l >> 2)) & 3;

  size_t abase[2], bbase[2];
#pragma unroll
  for (int p = 0; p < 2; ++p) {
    int r = r0 + ((p*4 + w) << 4) + srow;
    int bb = r >> 10, nn = (r & 1023) << 2;
    abase[p] = (((size_t)(bb*4102 + nn)) << 10) + schunk*8;
    int nc = n0 + ((p*4 + w) << 4) + srow;
    bbase[p] = (size_t)nc * 7168 + schunk*8;
  }

  f32x4 acc[4][4] = {};
  const int wm = (w >> 1) << 6, wn = (w & 1) << 6;
  const int quad = l >> 4, lc = l & 15, l3 = l & 3;

  for (int k0 = 0; k0 < 7168; k0 += 32) {
    __syncthreads();
#pragma unroll
    for (int p = 0; p < 2; ++p) {
      __builtin_amdgcn_global_load_lds((const AS1 void*)(Apad + abase[p] + k0),
                                       (AS3 void*)(As + ((p*4 + w) << 9)), 16, 0, 0);
      __builtin_amdgcn_global_load_lds((const AS1 void*)(WtQ + bbase[p] + k0),
                                       (AS3 void*)(Bs + ((p*4 + w) << 9)), 16, 0, 0);
    }
    __syncthreads();
    short8 af[4], bf[4];
    const int ch = (quad ^ l3) << 3;
#pragma unroll
    for (int i = 0; i < 4; ++i) {
      af[i] = *(const short8*)(As + (wm + (i<<4) + lc)*32 + ch);
      bf[i] = *(const short8*)(Bs + (wn + (i<<4) + lc)*32 + ch);
    }
#pragma unroll
    for (int i = 0; i < 4; ++i)
#pragma unroll
      for (int j = 0; j < 4; ++j)
        acc[i][j] = __builtin_amdgcn_mfma_f32_16x16x32_bf16(af[i], bf[j], acc[i][j], 0, 0, 0);
  }

#pragma unroll
  for (int i = 0; i < 4; ++i) {
    int rg = r0 + wm + (i<<4) + quad*4;
    int b = rg >> 10, mb = rg & 1023;
#pragma unroll
    for (int j = 0; j < 4; ++j) {
      int cg = n0 + wn + (j<<4) + lc;
      int h = cg >> 6, kd = (cg >> 5) & 1, d32 = cg & 31;
      size_t base = ((size_t)((b*16 + h)*2 + kd) * 1024 + mb) * 32 + d32;
#pragma unroll
      for (int rr = 0; rr < 4; ++rr) {
        float vv = acc[i][j][rr];
        Qsg[base + (size_t)rr*32] = f2bf(vv);
        Qf[((size_t)(rg + rr) << 10) + cg] = vv;
      }
    }
  }
}

// ---------- Flash attention: 64 q/block, N-tile=128, swizzled fragment staging ----------
__global__ __launch_bounds__(256) void attn_kernel(
    const unsigned short* __restrict__ Ksg, const unsigned short* __restrict__ Vsg,
    const unsigned short* __restrict__ Qsg, const float* __restrict__ Qf,
    float* __restrict__ out) {
  __shared__ unsigned short Ks[8192];   // [kd2][n128][32] swizzled
  __shared__ unsigned short Vs[8192];   // [kn4][d64][32] swizzled
  __shared__ unsigned short Qs[4096];   // [kd2][m64][32] swizzled
  __shared__ unsigned short Ps[8704];   // per-wave 16m x 136 (stride breaks conflicts)
  const int tid = threadIdx.x, w = tid >> 6, l = tid & 63;
  const int g = blockIdx.x;
  const int bh = (g & 7) + (((g >> 3) & 3) << 3);
  const int qt = g >> 5;
  const int b = bh >> 4, h = bh & 15;
  const int m0 = qt << 6;
  const int quad = l >> 4, lc = l & 15, l3 = l & 3;
  const float C = 0.18033688011112042f;  // log2(e)/8
  // swizzled staging source lane offset: row l>>2, chunk (l&3)^((l>>2)&3)
  const int lsw = (l & 60) | ((l ^ (l >> 2)) & 3);

  const unsigned short* KgT = Ksg + ((size_t)bh << 18);
  const unsigned short* VgT = Vsg + ((size_t)bh << 18);
  const unsigned short* QgT = Qsg + ((size_t)bh << 16);

#pragma unroll
  for (int p = 0; p < 2; ++p) {
    int t = w*2 + p;
    int kd = t >> 2, ml = (t & 3) << 4;
    __builtin_amdgcn_global_load_lds(
        (const AS1 void*)(QgT + ((size_t)((kd << 10) + m0 + ml) << 5) + lsw*8),
        (AS3 void*)(Qs + (t << 9)), 16, 0, 0);
  }

  float l_run = 0.f;
  f32x4 oacc[4] = {};
  unsigned short* Pw = Ps + w*2176;

  for (int it = 0; it < 32; ++it) {
    int n0 = it << 7;
    __syncthreads();
#pragma unroll
    for (int p = 0; p < 4; ++p) {
      int t = (w << 2) + p;
      __builtin_amdgcn_global_load_lds(
          (const AS1 void*)(KgT + ((size_t)(((t >> 3) << 12) + n0 + ((t & 7) << 4)) << 5) + lsw*8),
          (AS3 void*)(Ks + (t << 9)), 16, 0, 0);
      __builtin_amdgcn_global_load_lds(
          (const AS1 void*)(VgT + ((size_t)((((n0 >> 5) + (t >> 2)) << 6) + ((t & 3) << 4)) << 5) + lsw*8),
          (AS3 void*)(Vs + (t << 9)), 16, 0, 0);
    }
    __syncthreads();

    const int ch = (quad ^ l3) << 3;
    short8 ak[8][2];
#pragma unroll
    for (int k = 0; k < 2; ++k)
#pragma unroll
      for (int ni = 0; ni < 8; ++ni)
        ak[ni][k] = *(const short8*)(Ks + (k << 12) + ((ni<<4) + lc)*32 + ch);

    f32x4 sv[8] = {};
#pragma unroll
    for (int k = 0; k < 2; ++k) {
      short8 bq = *(const short8*)(Qs + (k << 11) + ((w<<4) + lc)*32 + ch);
#pragma unroll
      for (int ni = 0; ni < 8; ++ni)
        sv[ni] = __builtin_amdgcn_mfma_f32_16x16x32_bf16(ak[ni][k], bq, sv[ni], 0, 0, 0);
    }

    float su = 0.f;
#pragma unroll
    for (int ni = 0; ni < 8; ++ni) {
      u16x4 pv;
#pragma unroll
      for (int rr = 0; rr < 4; ++rr) {
        float pp = __builtin_amdgcn_exp2f(sv[ni][rr] * C);
        su += pp;
        pv[rr] = f2bf_fast(pp);
      }
      *(u16x4*)(Pw + lc*136 + (ni<<4) + (quad<<2)) = pv;
    }
    su += __shfl_xor(su, 16, 64);
    su += __shfl_xor(su, 32, 64);
    l_run += su;

#pragma unroll
    for (int kn = 0; kn < 4; ++kn) {
      short8 bp = *(const short8*)(Pw + lc*136 + (kn<<5) + (quad<<3));
#pragma unroll
      for (int dt = 0; dt < 4; ++dt) {
        short8 av = *(const short8*)(Vs + (kn << 11) + ((dt<<4) + lc)*32 + ch);
        oacc[dt] = __builtin_amdgcn_mfma_f32_16x16x32_bf16(av, bp, oacc[dt], 0, 0, 0);
      }
    }
  }

  float invl = 1.0f / l_run;
  int m = m0 + (w<<4) + lc;
#pragma unroll
  for (int dt = 0; dt < 4; ++dt) {
    int d = (dt<<4) + (quad<<2);
    size_t off = (((size_t)(b << 10) + m) << 10) + (h << 6) + d;
    f32x4 qv = *(const f32x4*)(Qf + off);
    f32x4 ov;
#pragma unroll
    for (int rr = 0; rr < 4; ++rr) ov[rr] = oacc[dt][rr]*invl + qv[rr];
    *(f32x4*)(out + off) = ov;
  }
}

extern "C" void kernel_launch(void* const* d_in, const int* in_sizes, int n_in,
                              void* d_out, int out_size, void* d_ws, size_t ws_size,
                              hipStream_t stream) {
  const float* x  = (const float*)d_in[0];
  const float* lw = (const float*)d_in[1];
  const float* lb = (const float*)d_in[2];
  const float* Wk = (const float*)d_in[3];
  const float* Wv = (const float*)d_in[4];
  const float* Wq = (const float*)d_in[5];
  float* out = (float*)d_out;

  char* ws = (char*)d_ws;
  size_t off = 0;
  unsigned short* xpad = (unsigned short*)(ws + off); off += (size_t)2*4102*1024*2;
  unsigned short* WtKV = (unsigned short*)(ws + off); off += (size_t)2048*7168*2;
  unsigned short* WtQ  = (unsigned short*)(ws + off); off += (size_t)1024*7168*2;
  unsigned short* Ksg  = (unsigned short*)(ws + off); off += (size_t)32*2*4096*32*2;
  unsigned short* Vsg  = (unsigned short*)(ws + off); off += (size_t)32*128*64*32*2;
  unsigned short* Qsg  = (unsigned short*)(ws + off); off += (size_t)32*2*1024*32*2;
  float*          Qf   = (float*)(ws + off);          off += (size_t)2048*1024*4;

  for (int b = 0; b < 2; ++b) {
    hipMemsetAsync(xpad + (size_t)b*4102*1024, 0, 3*1024*2, stream);
    hipMemsetAsync(xpad + ((size_t)b*4102 + 4099)*1024, 0, 3*1024*2, stream);
  }
  ln_kernel<<<dim3(8192), dim3(256), 0, stream>>>(x, lw, lb, xpad);
  repack_kernel<<<dim3(1024, 3), dim3(256), 0, stream>>>(Wk, Wv, Wq, WtKV, WtQ);
  conv_kv<<<dim3(1024), dim3(256), 0, stream>>>(xpad, WtKV, Ksg, Vsg);
  conv_q<<<dim3(8, 16), dim3(256), 0, stream>>>(xpad, WtQ, Qsg, Qf);
  attn_kernel<<<dim3(512), dim3(256), 0, stream>>>(Ksg, Vsg, Qsg, Qf, out);
}

// Round 6
// 575.047 us; speedup vs baseline: 1.2152x; 1.1736x over previous
//
#include <hip/hip_runtime.h>

typedef __attribute__((ext_vector_type(4))) float f32x4;
typedef __attribute__((ext_vector_type(16))) float f32x16;
typedef __attribute__((ext_vector_type(8))) short short8;
typedef __attribute__((ext_vector_type(4))) unsigned short u16x4;
typedef __attribute__((ext_vector_type(8))) unsigned short u16x8;

#define AS1 __attribute__((address_space(1)))
#define AS3 __attribute__((address_space(3)))

__device__ __forceinline__ unsigned short f2bf(float f) {
  unsigned u = __float_as_uint(f);
  return (unsigned short)((u + 0x7FFFu + ((u >> 16) & 1u)) >> 16);
}
__device__ __forceinline__ unsigned short f2bf_fast(float f) {
  return (unsigned short)((__float_as_uint(f) + 0x8000u) >> 16);
}

// ---------- LayerNorm fp32 -> bf16 into zero-padded (B, 3+N+3, D) ----------
__global__ __launch_bounds__(256) void ln_kernel(
    const float* __restrict__ x, const float* __restrict__ lw,
    const float* __restrict__ lb, unsigned short* __restrict__ xpad) {
  __shared__ float red[8];
  int row = blockIdx.x;                  // 0..8191
  int b = row >> 12, n = row & 4095;
  const float* xr = x + (size_t)row * 1024;
  int c = threadIdx.x * 4;
  f32x4 v = *(const f32x4*)(xr + c);
  float s = v[0] + v[1] + v[2] + v[3];
  float sq = v[0]*v[0] + v[1]*v[1] + v[2]*v[2] + v[3]*v[3];
#pragma unroll
  for (int off = 32; off; off >>= 1) {
    s  += __shfl_xor(s, off, 64);
    sq += __shfl_xor(sq, off, 64);
  }
  int w = threadIdx.x >> 6;
  if ((threadIdx.x & 63) == 0) { red[w*2] = s; red[w*2+1] = sq; }
  __syncthreads();
  float S  = red[0]+red[2]+red[4]+red[6];
  float SQ = red[1]+red[3]+red[5]+red[7];
  float mean = S * (1.0f/1024.0f);
  float var  = SQ * (1.0f/1024.0f) - mean*mean;
  float rstd = rsqrtf(var + 1e-5f);
  f32x4 wv = *(const f32x4*)(lw + c);
  f32x4 bv = *(const f32x4*)(lb + c);
  u16x4 o;
#pragma unroll
  for (int r = 0; r < 4; ++r) o[r] = f2bf((v[r]-mean)*rstd*wv[r] + bv[r]);
  *(u16x4*)(xpad + (((size_t)(b*4102 + n + 3)) << 10) + c) = o;
}

// ---------- Repack W (O,I,K) fp32 -> Wt rows (kk=k*1024+i) bf16 ----------
// Wt has 3072 rows: [0,1024)=Wk, [1024,2048)=Wv, [2048,3072)=Wq.
__global__ __launch_bounds__(256) void repack_kernel(
    const float* __restrict__ Wk, const float* __restrict__ Wv,
    const float* __restrict__ Wq, unsigned short* __restrict__ Wt) {
  __shared__ unsigned short t[7168];
  const float* W = (blockIdx.y == 0) ? Wk : (blockIdx.y == 1) ? Wv : Wq;
  int o = blockIdx.x;
  const float* row = W + (size_t)o * 7168;
  unsigned short* orow = Wt + ((size_t)(blockIdx.y * 1024 + o)) * 7168;
#pragma unroll
  for (int p = 0; p < 7; ++p) {
    int idx = p*1024 + threadIdx.x*4;
    f32x4 v = *(const f32x4*)(row + idx);
#pragma unroll
    for (int e = 0; e < 4; ++e) {
      unsigned j = idx + e;
      unsigned i = (j * 149797u) >> 20;   // j/7
      unsigned k = j - i*7;
      t[k*1024 + i] = f2bf(v[e]);
    }
  }
  __syncthreads();
#pragma unroll
  for (int p = 0; p < 7; ++p) {
    int idx = p*1024 + threadIdx.x*4;
    *(u16x4*)(orow + idx) = *(const u16x4*)(t + idx);
  }
}

// ---------- Unified conv GEMM: C = A(im2col) x Wt^T (N=3072), 32x32x16, BK=64 ----------
// g<1024: KV blocks (col panels 0..15, rows 8192). g>=1024: Q blocks (panels 16..23, rows 2048 strided).
// LDS: 128x64 halfword tiles; chunk c (16B) of row R stored at physical chunk c^(R&7).
__global__ __launch_bounds__(256, 4) void conv3(
    const unsigned short* __restrict__ Apad,
    const unsigned short* __restrict__ Wt,
    unsigned short* __restrict__ Ksg, unsigned short* __restrict__ Vsg,
    unsigned short* __restrict__ Qsg, float* __restrict__ Qf) {
  __shared__ unsigned short As[128*64];
  __shared__ unsigned short Bs[128*64];
  const int g = blockIdx.x;
  const int tid = threadIdx.x;
  const int w = tid >> 6, l = tid & 63;

  int mode, nt, rt;
  if (g < 1024) {
    int xcol = ((g & 7) << 1) | ((g >> 3) & 1);
    mode = (xcol < 8) ? 0 : 1;
    nt = xcol; rt = g >> 4;
  } else {
    int gq = g - 1024;
    mode = 2; nt = 16 + (gq & 7); rt = gq >> 3;
  }
  const int n0 = nt << 7;   // global output channel base [0,3072)
  const int r0 = rt << 7;   // row-tile base

  // staging: wave w loads rows [w*32, w*32+32) in 4 loads of 8 rows; lane row l>>3, src chunk cs
  const int lrow = l >> 3;
  const int cs = (l & 7) ^ lrow;
  size_t abase0, astep, bbase0;
  {
    int r = r0 + (w << 5) + lrow;
    int bb, nn;
    if (mode == 2) { bb = r >> 10; nn = (r & 1023) << 2; astep = 8 * 4096; }
    else           { bb = r >> 12; nn = r & 4095;        astep = 8 * 1024; }
    abase0 = (((size_t)(bb*4102 + nn)) << 10) + cs*8;
    int nc = n0 + (w << 5) + lrow;
    bbase0 = (size_t)nc * 7168 + cs*8;
  }

  f32x16 acc[2][2] = {};
  const int wm = (w >> 1) << 6, wn = (w & 1) << 6;   // wave quadrant (64x64)
  const int l31 = l & 31, lh = l >> 5, l7 = l & 7;

  for (int k0 = 0; k0 < 7168; k0 += 64) {
    __syncthreads();
#pragma unroll
    for (int t = 0; t < 4; ++t) {
      __builtin_amdgcn_global_load_lds((const AS1 void*)(Apad + abase0 + (size_t)t*astep + k0),
                                       (AS3 void*)(As + (((w << 2) + t) << 9)), 16, 0, 0);
      __builtin_amdgcn_global_load_lds((const AS1 void*)(Wt + bbase0 + (size_t)t*(8*7168) + k0),
                                       (AS3 void*)(Bs + (((w << 2) + t) << 9)), 16, 0, 0);
    }
    __syncthreads();
#pragma unroll
    for (int s2 = 0; s2 < 2; ++s2) {
      short8 af[2][2], bf[2][2];   // [tile][k16-half within s2]
#pragma unroll
      for (int i = 0; i < 2; ++i)
#pragma unroll
        for (int hs = 0; hs < 2; ++hs) {
          int s = (s2 << 1) | hs;              // 0..3
          int ch = (((s << 1) | lh) ^ l7) << 3;
          af[i][hs] = *(const short8*)(As + (wm + (i<<5) + l31)*64 + ch);
          bf[i][hs] = *(const short8*)(Bs + (wn + (i<<5) + l31)*64 + ch);
        }
#pragma unroll
      for (int hs = 0; hs < 2; ++hs)
#pragma unroll
        for (int i = 0; i < 2; ++i)
#pragma unroll
          for (int j = 0; j < 2; ++j)
            acc[i][j] = __builtin_amdgcn_mfma_f32_32x32x16_bf16(af[i][hs], bf[j][hs], acc[i][j], 0, 0, 0);
    }
  }

  // C/D mapping (32x32): col = l&31, row = (r&3) + 8*(r>>2) + 4*(l>>5)
  if (mode == 0) {   // K -> Ksg[bh][kd2][n4096][32]
#pragma unroll
    for (int i = 0; i < 2; ++i) {
      int rgb = r0 + wm + (i<<5);
      int b = rgb >> 12, nbase = rgb & 4095;
#pragma unroll
      for (int j = 0; j < 2; ++j) {
        int cg = n0 + wn + (j<<5) + l31;
        int h = cg >> 6, kd = (cg >> 5) & 1;
        size_t base = ((size_t)(((b*16 + h)*2 + kd)) << 12) * 32 + (size_t)(cg & 31);
#pragma unroll
        for (int r = 0; r < 16; ++r) {
          int nb = nbase + (r & 3) + ((r >> 2) << 3) + (lh << 2);
          Ksg[base + ((size_t)nb << 5)] = f2bf(acc[i][j][r]);
        }
      }
    }
  } else if (mode == 1) {   // V -> Vsg[bh][n>>5][d][n&31]
#pragma unroll
    for (int i = 0; i < 2; ++i) {
      int rgb = r0 + wm + (i<<5);
      int b = rgb >> 12, nbase = rgb & 4095;
      int nc = nbase >> 5;
#pragma unroll
      for (int j = 0; j < 2; ++j) {
        int c = n0 + wn + (j<<5) + l31 - 1024;
        int h = c >> 6, d = c & 63;
        size_t rowbase = ((size_t)((b*16 + h)*128 + nc) * 64 + d) << 5;
#pragma unroll
        for (int g2 = 0; g2 < 4; ++g2) {
          u16x4 pv;
#pragma unroll
          for (int e = 0; e < 4; ++e) pv[e] = f2bf(acc[i][j][g2*4 + e]);
          *(u16x4*)(Vsg + rowbase + (g2 << 3) + (lh << 2)) = pv;
        }
      }
    }
  } else {   // Q -> Qsg[bh][kd2][m1024][32] + Qf row-major fp32
#pragma unroll
    for (int i = 0; i < 2; ++i) {
      int rqb = r0 + wm + (i<<5);
#pragma unroll
      for (int j = 0; j < 2; ++j) {
        int cg = (n0 - 2048) + wn + (j<<5) + l31;
        int h = cg >> 6, kd = (cg >> 5) & 1, d32 = cg & 31;
#pragma unroll
        for (int r = 0; r < 16; ++r) {
          int rq = rqb + (r & 3) + ((r >> 2) << 3) + (lh << 2);
          int b = rq >> 10, m = rq & 1023;
          float vv = acc[i][j][r];
          Qsg[(((size_t)((b*16 + h)*2 + kd) * 1024 + m) << 5) + d32] = f2bf(vv);
          Qf[((size_t)rq << 10) + cg] = vv;
        }
      }
    }
  }
}

// ---------- Flash attention: 64 q/block, N-tile=128, swizzled fragment staging ----------
__global__ __launch_bounds__(256) void attn_kernel(
    const unsigned short* __restrict__ Ksg, const unsigned short* __restrict__ Vsg,
    const unsigned short* __restrict__ Qsg, const float* __restrict__ Qf,
    float* __restrict__ out) {
  __shared__ unsigned short Ks[8192];   // [kd2][n128][32] swizzled
  __shared__ unsigned short Vs[8192];   // [kn4][d64][32] swizzled
  __shared__ unsigned short Qs[4096];   // [kd2][m64][32] swizzled
  __shared__ unsigned short Ps[8704];   // per-wave 16m x 136
  const int tid = threadIdx.x, w = tid >> 6, l = tid & 63;
  const int g = blockIdx.x;
  const int bh = (g & 7) + (((g >> 3) & 3) << 3);
  const int qt = g >> 5;
  const int b = bh >> 4, h = bh & 15;
  const int m0 = qt << 6;
  const int quad = l >> 4, lc = l & 15, l3 = l & 3;
  const float C = 0.18033688011112042f;  // log2(e)/8
  const int lsw = (l & 60) | ((l ^ (l >> 2)) & 3);

  const unsigned short* KgT = Ksg + ((size_t)bh << 18);
  const unsigned short* VgT = Vsg + ((size_t)bh << 18);
  const unsigned short* QgT = Qsg + ((size_t)bh << 16);

#pragma unroll
  for (int p = 0; p < 2; ++p) {
    int t = w*2 + p;
    int kd = t >> 2, ml = (t & 3) << 4;
    __builtin_amdgcn_global_load_lds(
        (const AS1 void*)(QgT + ((size_t)((kd << 10) + m0 + ml) << 5) + lsw*8),
        (AS3 void*)(Qs + (t << 9)), 16, 0, 0);
  }

  float l_run = 0.f;
  f32x4 oacc[4] = {};
  unsigned short* Pw = Ps + w*2176;

  for (int it = 0; it < 32; ++it) {
    int n0 = it << 7;
    __syncthreads();
#pragma unroll
    for (int p = 0; p < 4; ++p) {
      int t = (w << 2) + p;
      __builtin_amdgcn_global_load_lds(
          (const AS1 void*)(KgT + ((size_t)(((t >> 3) << 12) + n0 + ((t & 7) << 4)) << 5) + lsw*8),
          (AS3 void*)(Ks + (t << 9)), 16, 0, 0);
      __builtin_amdgcn_global_load_lds(
          (const AS1 void*)(VgT + ((size_t)((((n0 >> 5) + (t >> 2)) << 6) + ((t & 3) << 4)) << 5) + lsw*8),
          (AS3 void*)(Vs + (t << 9)), 16, 0, 0);
    }
    __syncthreads();

    const int ch = (quad ^ l3) << 3;
    short8 ak[8][2];
#pragma unroll
    for (int k = 0; k < 2; ++k)
#pragma unroll
      for (int ni = 0; ni < 8; ++ni)
        ak[ni][k] = *(const short8*)(Ks + (k << 12) + ((ni<<4) + lc)*32 + ch);

    f32x4 sv[8] = {};
#pragma unroll
    for (int k = 0; k < 2; ++k) {
      short8 bq = *(const short8*)(Qs + (k << 11) + ((w<<4) + lc)*32 + ch);
#pragma unroll
      for (int ni = 0; ni < 8; ++ni)
        sv[ni] = __builtin_amdgcn_mfma_f32_16x16x32_bf16(ak[ni][k], bq, sv[ni], 0, 0, 0);
    }

    float su = 0.f;
#pragma unroll
    for (int ni = 0; ni < 8; ++ni) {
      u16x4 pv;
#pragma unroll
      for (int rr = 0; rr < 4; ++rr) {
        float pp = __builtin_amdgcn_exp2f(sv[ni][rr] * C);
        su += pp;
        pv[rr] = f2bf_fast(pp);
      }
      *(u16x4*)(Pw + lc*136 + (ni<<4) + (quad<<2)) = pv;
    }
    su += __shfl_xor(su, 16, 64);
    su += __shfl_xor(su, 32, 64);
    l_run += su;

#pragma unroll
    for (int kn = 0; kn < 4; ++kn) {
      short8 bp = *(const short8*)(Pw + lc*136 + (kn<<5) + (quad<<3));
#pragma unroll
      for (int dt = 0; dt < 4; ++dt) {
        short8 av = *(const short8*)(Vs + (kn << 11) + ((dt<<4) + lc)*32 + ch);
        oacc[dt] = __builtin_amdgcn_mfma_f32_16x16x32_bf16(av, bp, oacc[dt], 0, 0, 0);
      }
    }
  }

  float invl = 1.0f / l_run;
  int m = m0 + (w<<4) + lc;
#pragma unroll
  for (int dt = 0; dt < 4; ++dt) {
    int d = (dt<<4) + (quad<<2);
    size_t off = (((size_t)(b << 10) + m) << 10) + (h << 6) + d;
    f32x4 qv = *(const f32x4*)(Qf + off);
    f32x4 ov;
#pragma unroll
    for (int rr = 0; rr < 4; ++rr) ov[rr] = oacc[dt][rr]*invl + qv[rr];
    *(f32x4*)(out + off) = ov;
  }
}

extern "C" void kernel_launch(void* const* d_in, const int* in_sizes, int n_in,
                              void* d_out, int out_size, void* d_ws, size_t ws_size,
                              hipStream_t stream) {
  const float* x  = (const float*)d_in[0];
  const float* lw = (const float*)d_in[1];
  const float* lb = (const float*)d_in[2];
  const float* Wk = (const float*)d_in[3];
  const float* Wv = (const float*)d_in[4];
  const float* Wq = (const float*)d_in[5];
  float* out = (float*)d_out;

  char* ws = (char*)d_ws;
  size_t off = 0;
  unsigned short* xpad = (unsigned short*)(ws + off); off += (size_t)2*4102*1024*2;
  unsigned short* Wt   = (unsigned short*)(ws + off); off += (size_t)3072*7168*2;
  unsigned short* Ksg  = (unsigned short*)(ws + off); off += (size_t)32*2*4096*32*2;
  unsigned short* Vsg  = (unsigned short*)(ws + off); off += (size_t)32*128*64*32*2;
  unsigned short* Qsg  = (unsigned short*)(ws + off); off += (size_t)32*2*1024*32*2;
  float*          Qf   = (float*)(ws + off);          off += (size_t)2048*1024*4;

  for (int b = 0; b < 2; ++b) {
    hipMemsetAsync(xpad + (size_t)b*4102*1024, 0, 3*1024*2, stream);
    hipMemsetAsync(xpad + ((size_t)b*4102 + 4099)*1024, 0, 3*1024*2, stream);
  }
  ln_kernel<<<dim3(8192), dim3(256), 0, stream>>>(x, lw, lb, xpad);
  repack_kernel<<<dim3(1024, 3), dim3(256), 0, stream>>>(Wk, Wv, Wq, Wt);
  conv3<<<dim3(1152), dim3(256), 0, stream>>>(xpad, Wt, Ksg, Vsg, Qsg, Qf);
  attn_kernel<<<dim3(512), dim3(256), 0, stream>>>(Ksg, Vsg, Qsg, Qf, out);
}